// Round 1
// baseline (163.502 us; speedup 1.0000x reference)
//
#include <hip/hip_runtime.h>
#include <hip/hip_bf16.h>
#include <stdint.h>

#define B_DIM 4096
#define T_DIM 8
#define IN_DIM 1024
#define OUT_DIM 1024
#define R_DIM 32

#define BM 128
#define BN 128
#define BK 64
#define NKT (IN_DIM / BK)   // 16

typedef __bf16 bf16x8 __attribute__((ext_vector_type(8)));
typedef float  f32x4  __attribute__((ext_vector_type(4)));

// ---- helpers --------------------------------------------------------------

// round-to-nearest fp32->bf16, two packed into one u32 (lo in low half)
__device__ __forceinline__ uint32_t pack2_bf16(float a, float b) {
  uint32_t ua = __float_as_uint(a), ub = __float_as_uint(b);
  ua = (ua + 0x7FFFu + ((ua >> 16) & 1u)) >> 16;
  ub = (ub + 0x7FFFu + ((ub >> 16) & 1u)) & 0xFFFF0000u;
  return ua | ub;
}

// async global->LDS, 16B per lane; LDS dest is wave-uniform base + lane*16
__device__ __forceinline__ void gload_lds16(const void* g, void* l) {
  __builtin_amdgcn_global_load_lds(
      (const __attribute__((address_space(1))) void*)(uintptr_t)g,
      (__attribute__((address_space(3))) void*)(uint32_t)(uintptr_t)l,
      16, 0, 0);
}

// ---- kernel 1: A1[t][i][k] = sum_j first[t][j] * middle[j][i][k] ----------
// grid 1024 x 256; fully coalesced over (i,k); trivial cost
__global__ void tt_stage1(const float* __restrict__ first,
                          const float* __restrict__ middle,
                          float* __restrict__ a1) {
  int idx = blockIdx.x * 256 + threadIdx.x;     // t*32768 + i*32 + k
  int t  = idx >> 15;
  int ik = idx & 32767;
  float acc = 0.f;
#pragma unroll
  for (int j = 0; j < R_DIM; ++j)
    acc = fmaf(first[t * R_DIM + j], middle[j * (IN_DIM * R_DIM) + ik], acc);
  a1[idx] = acc;
}

// ---- kernel 2: w_T[t][o][i] = sum_k A1[t][i][k]*task[k][o], bf16 ----------
// transposed (o-major) layout so GEMM B-staging has contiguous k per n-row.
// grid 2048 (8 t x 16 ob x 16 ib) x 256
__global__ __launch_bounds__(256) void tt_stage2(const float* __restrict__ a1,
                                                 const float* __restrict__ task,
                                                 __hip_bfloat16* __restrict__ wT) {
  int bid = blockIdx.x;
  int t  = bid >> 8;
  int ob = (bid >> 4) & 15;
  int ib = bid & 15;
  __shared__ float A1s[64][33];   // +1 pad: i-indexed reads conflict-free
  __shared__ float Ts[32][64];
  int tid = threadIdx.x;
#pragma unroll
  for (int r = 0; r < 8; ++r) {
    int idx2 = tid + 256 * r;              // 64x32 A1 tile
    int il = idx2 >> 5, k = idx2 & 31;
    A1s[il][k] = a1[t * (IN_DIM * R_DIM) + (ib * 64 + il) * R_DIM + k];
  }
#pragma unroll
  for (int r = 0; r < 8; ++r) {
    int idx2 = tid + 256 * r;              // 32x64 task tile
    int k = idx2 >> 6, ol = idx2 & 63;
    Ts[k][ol] = task[k * OUT_DIM + ob * 64 + ol];
  }
  __syncthreads();
  int il = tid & 63;
  int og = tid >> 6;                        // 0..3
  float acc[16];
#pragma unroll
  for (int r = 0; r < 16; ++r) acc[r] = 0.f;
#pragma unroll
  for (int k = 0; k < 32; ++k) {
    float a = A1s[il][k];
#pragma unroll
    for (int r = 0; r < 16; ++r)
      acc[r] = fmaf(a, Ts[k][og * 16 + r], acc[r]);   // Ts broadcast in-wave
  }
#pragma unroll
  for (int r = 0; r < 16; ++r) {
    size_t o = (size_t)ob * 64 + og * 16 + r;
    wT[((size_t)t * OUT_DIM + o) * IN_DIM + ib * 64 + il] = __float2bfloat16(acc[r]);
  }
}

// ---- kernel 3: per-task GEMM, bf16 MFMA, 128x128xBK64, dbuf LDS -----------
// LDS map (dynamic 64KB): A[2][128][64]bf16 at 0, B[2][128(n)][64(k)]bf16 at 32768
// XOR swizzle within 128B rows: byte_in_row ^= (row&7)<<4 (both write & read)
__global__ __launch_bounds__(256, 2) void tt_gemm(const float* __restrict__ X,
                                                  const uint16_t* __restrict__ WT,
                                                  float* __restrict__ O) {
  extern __shared__ uint8_t sm[];

  const int nwg = T_DIM * (B_DIM / BM) * (OUT_DIM / BN);  // 2048
  const int cpx = nwg >> 3;                               // 256 = one full task
  int bid = blockIdx.x;
  int l  = (bid & 7) * cpx + (bid >> 3);   // bijective XCD swizzle: XCD == t
  int t  = l >> 8;
  int mt = (l >> 3) & 31;
  int nt = l & 7;                          // n fastest -> x panel shared in L2

  const int tid  = threadIdx.x;
  const int lane = tid & 63;
  const int wave = tid >> 6;
  const int wr = wave >> 1, wc = wave & 1;

  // A staging: 16 threads/row-segment (16B fp32 each), rows tid>>4 + 16r
  const int a_row  = tid >> 4;
  const int a_col4 = tid & 15;
  const float* xbase =
      X + ((size_t)(mt * BM) * T_DIM + t) * IN_DIM + a_col4 * 4;

  // B staging (global_load_lds): region = wave*4+q holds 8 rows of 128B
  const int b_rowin = lane >> 3;           // row within region
  const int b_c     = lane & 7;            // 16B chunk
  const int b_gcol  = (b_c * 16) ^ (b_rowin << 4);  // inverse-swizzled source
  const uint16_t* wtile = WT + ((size_t)(t * OUT_DIM + nt * BN)) * IN_DIM;

  // fragment read params (16x16x32: row = lane&15, k-chunk = lane>>4)
  const int r0a  = wr * 64 + (lane & 15);
  const int r0b  = wc * 64 + (lane & 15);
  const int kswz = (lane & 7) << 4;
  const int kg   = lane >> 4;

  f32x4 acc[4][4] = {};
  float4 areg[8];

  // ---- prologue: stage kt=0 into buf0, preload A(1) into regs
#pragma unroll
  for (int r = 0; r < 8; ++r)
    areg[r] = *(const float4*)(xbase + (size_t)(a_row + 16 * r) * (T_DIM * IN_DIM));
#pragma unroll
  for (int q = 0; q < 4; ++q) {
    int row = (wave * 4 + q) * 8 + b_rowin;
    gload_lds16((const uint8_t*)(wtile + (size_t)row * IN_DIM) + b_gcol,
                sm + 32768 + (wave * 4 + q) * 1024);
  }
#pragma unroll
  for (int r = 0; r < 8; ++r) {
    int row = a_row + 16 * r;
    uint2 v;
    v.x = pack2_bf16(areg[r].x, areg[r].y);
    v.y = pack2_bf16(areg[r].z, areg[r].w);
    *(uint2*)(sm + row * 128 + ((a_col4 * 8) ^ ((row & 7) << 4))) = v;
  }
#pragma unroll
  for (int r = 0; r < 8; ++r)
    areg[r] = *(const float4*)(xbase + BK + (size_t)(a_row + 16 * r) * (T_DIM * IN_DIM));

  // ---- main loop: one barrier per K-step, both operands prefetched 1 ahead
#pragma unroll 2
  for (int kt = 0; kt < NKT; ++kt) {
    __syncthreads();                        // buf[cur] staged & prev reads done
    const int cur = kt & 1;
    const int nxt = cur ^ 1;
    if (kt + 1 < NKT) {
      const uint16_t* wk = wtile + (size_t)(kt + 1) * BK;
#pragma unroll
      for (int q = 0; q < 4; ++q) {
        int row = (wave * 4 + q) * 8 + b_rowin;
        gload_lds16((const uint8_t*)(wk + (size_t)row * IN_DIM) + b_gcol,
                    sm + 32768 + nxt * 16384 + (wave * 4 + q) * 1024);
      }
      uint8_t* abase = sm + nxt * 16384;
#pragma unroll
      for (int r = 0; r < 8; ++r) {
        int row = a_row + 16 * r;
        uint2 v;
        v.x = pack2_bf16(areg[r].x, areg[r].y);
        v.y = pack2_bf16(areg[r].z, areg[r].w);
        *(uint2*)(abase + row * 128 + ((a_col4 * 8) ^ ((row & 7) << 4))) = v;
      }
      if (kt + 2 < NKT) {
        const float* xk = xbase + (size_t)(kt + 2) * BK;
#pragma unroll
        for (int r = 0; r < 8; ++r)
          areg[r] = *(const float4*)(xk + (size_t)(a_row + 16 * r) * (T_DIM * IN_DIM));
      }
    }
    const uint8_t* ab = sm + cur * 16384;
    const uint8_t* bb = sm + 32768 + cur * 16384;
#pragma unroll
    for (int ks = 0; ks < 2; ++ks) {
      const int kbyte = (ks * 64 + kg * 16) ^ kswz;
      bf16x8 af[4], bfr[4];
#pragma unroll
      for (int m = 0; m < 4; ++m)
        af[m] = *(const bf16x8*)(ab + (r0a + m * 16) * 128 + kbyte);
#pragma unroll
      for (int n = 0; n < 4; ++n)
        bfr[n] = *(const bf16x8*)(bb + (r0b + n * 16) * 128 + kbyte);
#pragma unroll
      for (int m = 0; m < 4; ++m)
#pragma unroll
        for (int n = 0; n < 4; ++n)
          acc[m][n] = __builtin_amdgcn_mfma_f32_16x16x32_bf16(af[m], bfr[n],
                                                              acc[m][n], 0, 0, 0);
    }
  }

  // ---- epilogue: C/D layout col=lane&15, row=(lane>>4)*4+j (m89-verified)
  const size_t obase =
      (size_t)(mt * BM) * (T_DIM * OUT_DIM) + (size_t)t * OUT_DIM + nt * BN;
  const int crow0 = wr * 64 + (lane >> 4) * 4;
  const int ccol  = wc * 64 + (lane & 15);
#pragma unroll
  for (int m = 0; m < 4; ++m) {
#pragma unroll
    for (int j = 0; j < 4; ++j) {
      size_t rowoff = obase + (size_t)(crow0 + m * 16 + j) * (T_DIM * OUT_DIM) + ccol;
#pragma unroll
      for (int n = 0; n < 4; ++n)
        O[rowoff + n * 16] = acc[m][n][j];
    }
  }
}

// ---- host ------------------------------------------------------------------
extern "C" void kernel_launch(void* const* d_in, const int* in_sizes, int n_in,
                              void* d_out, int out_size, void* d_ws, size_t ws_size,
                              hipStream_t stream) {
  const float* x      = (const float*)d_in[0];
  const float* first  = (const float*)d_in[1];
  const float* middle = (const float*)d_in[2];
  const float* task   = (const float*)d_in[3];
  float* out = (float*)d_out;

  // ws: A1 fp32 [8][1024][32] = 1MB at 0; w_T bf16 [8][1024][1024] = 16MB at 1MB
  float* a1 = (float*)d_ws;
  __hip_bfloat16* wT = (__hip_bfloat16*)((uint8_t*)d_ws + (1u << 20));

  tt_stage1<<<(T_DIM * IN_DIM * R_DIM) / 256, 256, 0, stream>>>(first, middle, a1);
  tt_stage2<<<T_DIM * 16 * 16, 256, 0, stream>>>(a1, task, wT);
  tt_gemm<<<T_DIM * (B_DIM / BM) * (OUT_DIM / BN), 256, 65536, stream>>>(
      x, (const uint16_t*)wT, out);
}

// Round 2
// 144.241 us; speedup vs baseline: 1.1335x; 1.1335x over previous
//
#include <hip/hip_runtime.h>
#include <hip/hip_bf16.h>
#include <stdint.h>

#define B_DIM 4096
#define T_DIM 8
#define IN_DIM 1024
#define OUT_DIM 1024
#define R_DIM 32

#define BM 128
#define BN 128
#define BK 64
#define NKT (IN_DIM / BK)   // 16

typedef __bf16 bf16x8 __attribute__((ext_vector_type(8)));
typedef float  f32x4  __attribute__((ext_vector_type(4)));

// ---- helpers --------------------------------------------------------------

// round-to-nearest fp32->bf16, two packed into one u32 (lo in low half)
__device__ __forceinline__ uint32_t pack2_bf16(float a, float b) {
  uint32_t ua = __float_as_uint(a), ub = __float_as_uint(b);
  ua = (ua + 0x7FFFu + ((ua >> 16) & 1u)) >> 16;
  ub = (ub + 0x7FFFu + ((ub >> 16) & 1u)) & 0xFFFF0000u;
  return ua | ub;
}

// async global->LDS, 16B per lane; LDS dest is wave-uniform base + lane*16
__device__ __forceinline__ void gload_lds16(const void* g, void* l) {
  __builtin_amdgcn_global_load_lds(
      (const __attribute__((address_space(1))) void*)(uintptr_t)g,
      (__attribute__((address_space(3))) void*)(uint32_t)(uintptr_t)l,
      16, 0, 0);
}

// ---- kernel 1: A1[t][i][k] = sum_j first[t][j] * middle[j][i][k] ----------
__global__ void tt_stage1(const float* __restrict__ first,
                          const float* __restrict__ middle,
                          float* __restrict__ a1) {
  int idx = blockIdx.x * 256 + threadIdx.x;     // t*32768 + i*32 + k
  int t  = idx >> 15;
  int ik = idx & 32767;
  float acc = 0.f;
#pragma unroll
  for (int j = 0; j < R_DIM; ++j)
    acc = fmaf(first[t * R_DIM + j], middle[j * (IN_DIM * R_DIM) + ik], acc);
  a1[idx] = acc;
}

// ---- kernel 2: w_T[t][o][i] = sum_k A1[t][i][k]*task[k][o], bf16 ----------
__global__ __launch_bounds__(256) void tt_stage2(const float* __restrict__ a1,
                                                 const float* __restrict__ task,
                                                 __hip_bfloat16* __restrict__ wT) {
  int bid = blockIdx.x;
  int t  = bid >> 8;
  int ob = (bid >> 4) & 15;
  int ib = bid & 15;
  __shared__ float A1s[64][33];
  __shared__ float Ts[32][64];
  int tid = threadIdx.x;
#pragma unroll
  for (int r = 0; r < 8; ++r) {
    int idx2 = tid + 256 * r;              // 64x32 A1 tile
    int il = idx2 >> 5, k = idx2 & 31;
    A1s[il][k] = a1[t * (IN_DIM * R_DIM) + (ib * 64 + il) * R_DIM + k];
  }
#pragma unroll
  for (int r = 0; r < 8; ++r) {
    int idx2 = tid + 256 * r;              // 32x64 task tile
    int k = idx2 >> 6, ol = idx2 & 63;
    Ts[k][ol] = task[k * OUT_DIM + ob * 64 + ol];
  }
  __syncthreads();
  int il = tid & 63;
  int og = tid >> 6;                        // 0..3
  float acc[16];
#pragma unroll
  for (int r = 0; r < 16; ++r) acc[r] = 0.f;
#pragma unroll
  for (int k = 0; k < 32; ++k) {
    float a = A1s[il][k];
#pragma unroll
    for (int r = 0; r < 16; ++r)
      acc[r] = fmaf(a, Ts[k][og * 16 + r], acc[r]);
  }
#pragma unroll
  for (int r = 0; r < 16; ++r) {
    size_t o = (size_t)ob * 64 + og * 16 + r;
    wT[((size_t)t * OUT_DIM + o) * IN_DIM + ib * 64 + il] = __float2bfloat16(acc[r]);
  }
}

// ---- kernel 3: per-task GEMM, bf16 MFMA, 128x128xBK64, SINGLE-buffer LDS --
// LDS map (dynamic 32KB): A[128][64]bf16 at 0, B[128(n)][64(k)]bf16 at 16384
// XOR swizzle within 128B rows: byte_in_row ^= (row&7)<<4 (both write & read)
// m97 structure: stage -> barrier(drains vmcnt) -> compute (+A-reg prefetch)
// -> barrier. Overlap comes from ~3 blocks/CU co-residency, not src dbuf.
__global__ __launch_bounds__(256, 3) void tt_gemm(const float* __restrict__ X,
                                                  const uint16_t* __restrict__ WT,
                                                  float* __restrict__ O) {
  extern __shared__ uint8_t sm[];

  const int cpx = (T_DIM * (B_DIM / BM) * (OUT_DIM / BN)) >> 3;  // 256
  int bid = blockIdx.x;
  int l  = (bid & 7) * cpx + (bid >> 3);   // bijective XCD swizzle: XCD == t
  int t  = l >> 8;
  int mt = (l >> 3) & 31;
  int nt = l & 7;                          // n fastest -> x panel shared in L2

  const int tid  = threadIdx.x;
  const int lane = tid & 63;
  const int wave = tid >> 6;
  const int wr = wave >> 1, wc = wave & 1;

  // A staging: 16 threads/row-segment (16B fp32 each), rows tid>>4 + 16r
  const int a_row  = tid >> 4;
  const int a_col4 = tid & 15;
  const float* xbase =
      X + ((size_t)(mt * BM) * T_DIM + t) * IN_DIM + a_col4 * 4;

  // B staging (global_load_lds): region = wave*4+q holds 8 rows of 128B
  const int b_rowin = lane >> 3;           // row within region
  const int b_c     = lane & 7;            // 16B chunk
  const int b_gcol  = (b_c * 16) ^ (b_rowin << 4);  // inverse-swizzled source
  const uint16_t* wtile = WT + ((size_t)(t * OUT_DIM + nt * BN)) * IN_DIM;

  // fragment read params (16x16x32: row = lane&15, k-chunk = lane>>4)
  const int r0a  = wr * 64 + (lane & 15);
  const int r0b  = wc * 64 + (lane & 15);
  const int kswz = (lane & 7) << 4;
  const int kg   = lane >> 4;

  f32x4 acc[4][4] = {};
  float4 areg[8];

  // prologue: A tile kt=0 into regs
#pragma unroll
  for (int r = 0; r < 8; ++r)
    areg[r] = *(const float4*)(xbase + (size_t)(a_row + 16 * r) * (T_DIM * IN_DIM));

  for (int kt = 0; kt < NKT; ++kt) {
    // ---- stage: pack+write A regs, issue async B loads
#pragma unroll
    for (int r = 0; r < 8; ++r) {
      int row = a_row + 16 * r;
      uint2 v;
      v.x = pack2_bf16(areg[r].x, areg[r].y);
      v.y = pack2_bf16(areg[r].z, areg[r].w);
      *(uint2*)(sm + row * 128 + ((a_col4 * 8) ^ ((row & 7) << 4))) = v;
    }
    {
      const uint16_t* wk = wtile + (size_t)kt * BK;
#pragma unroll
      for (int q = 0; q < 4; ++q) {
        int row = (wave * 4 + q) * 8 + b_rowin;
        gload_lds16((const uint8_t*)(wk + (size_t)row * IN_DIM) + b_gcol,
                    sm + 16384 + (wave * 4 + q) * 1024);
      }
    }
    __syncthreads();   // drains vmcnt(0)+lgkmcnt: A,B fully in LDS

    // ---- prefetch next A tile into regs (drains at bottom barrier,
    //      exactly where they're next consumed)
    if (kt + 1 < NKT) {
      const float* xk = xbase + (size_t)(kt + 1) * BK;
#pragma unroll
      for (int r = 0; r < 8; ++r)
        areg[r] = *(const float4*)(xk + (size_t)(a_row + 16 * r) * (T_DIM * IN_DIM));
    }

    // ---- compute 32 MFMA from LDS
    const uint8_t* ab = sm;
    const uint8_t* bb = sm + 16384;
#pragma unroll
    for (int ks = 0; ks < 2; ++ks) {
      const int kbyte = (ks * 64 + kg * 16) ^ kswz;
      bf16x8 af[4], bfr[4];
#pragma unroll
      for (int m = 0; m < 4; ++m)
        af[m] = *(const bf16x8*)(ab + (r0a + m * 16) * 128 + kbyte);
#pragma unroll
      for (int n = 0; n < 4; ++n)
        bfr[n] = *(const bf16x8*)(bb + (r0b + n * 16) * 128 + kbyte);
#pragma unroll
      for (int m = 0; m < 4; ++m)
#pragma unroll
        for (int n = 0; n < 4; ++n)
          acc[m][n] = __builtin_amdgcn_mfma_f32_16x16x32_bf16(af[m], bfr[n],
                                                              acc[m][n], 0, 0, 0);
    }
    __syncthreads();   // LDS reads done before next iteration overwrites
  }

  // ---- epilogue: C/D layout col=lane&15, row=(lane>>4)*4+j (m89-verified)
  const size_t obase =
      (size_t)(mt * BM) * (T_DIM * OUT_DIM) + (size_t)t * OUT_DIM + nt * BN;
  const int crow0 = wr * 64 + (lane >> 4) * 4;
  const int ccol  = wc * 64 + (lane & 15);
#pragma unroll
  for (int m = 0; m < 4; ++m) {
#pragma unroll
    for (int j = 0; j < 4; ++j) {
      size_t rowoff = obase + (size_t)(crow0 + m * 16 + j) * (T_DIM * OUT_DIM) + ccol;
#pragma unroll
      for (int n = 0; n < 4; ++n)
        O[rowoff + n * 16] = acc[m][n][j];
    }
  }
}

// ---- host ------------------------------------------------------------------
extern "C" void kernel_launch(void* const* d_in, const int* in_sizes, int n_in,
                              void* d_out, int out_size, void* d_ws, size_t ws_size,
                              hipStream_t stream) {
  const float* x      = (const float*)d_in[0];
  const float* first  = (const float*)d_in[1];
  const float* middle = (const float*)d_in[2];
  const float* task   = (const float*)d_in[3];
  float* out = (float*)d_out;

  // ws: A1 fp32 [8][1024][32] = 1MB at 0; w_T bf16 [8][1024][1024] = 16MB at 1MB
  float* a1 = (float*)d_ws;
  __hip_bfloat16* wT = (__hip_bfloat16*)((uint8_t*)d_ws + (1u << 20));

  tt_stage1<<<(T_DIM * IN_DIM * R_DIM) / 256, 256, 0, stream>>>(first, middle, a1);
  tt_stage2<<<T_DIM * 16 * 16, 256, 0, stream>>>(a1, task, wT);
  tt_gemm<<<T_DIM * (B_DIM / BM) * (OUT_DIM / BN), 256, 32768, stream>>>(
      x, (const uint16_t*)wT, out);
}

// Round 3
// 139.532 us; speedup vs baseline: 1.1718x; 1.0337x over previous
//
#include <hip/hip_runtime.h>
#include <hip/hip_bf16.h>
#include <stdint.h>

#define B_DIM 4096
#define T_DIM 8
#define IN_DIM 1024
#define OUT_DIM 1024
#define R_DIM 32

#define BM 128
#define BN 128
#define BK 64
#define NKT (IN_DIM / BK)   // 16

typedef __bf16 bf16x8 __attribute__((ext_vector_type(8)));
typedef float  f32x4  __attribute__((ext_vector_type(4)));

// ---- helpers --------------------------------------------------------------

// async global->LDS, 16B per lane; LDS dest is wave-uniform base + lane*16
__device__ __forceinline__ void gload_lds16(const void* g, void* l) {
  __builtin_amdgcn_global_load_lds(
      (const __attribute__((address_space(1))) void*)(uintptr_t)g,
      (__attribute__((address_space(3))) void*)(uint32_t)(uintptr_t)l,
      16, 0, 0);
}

// ---- kernel 1: A1[t][i][k] = sum_j first[t][j] * middle[j][i][k] ----------
__global__ void tt_stage1(const float* __restrict__ first,
                          const float* __restrict__ middle,
                          float* __restrict__ a1) {
  int idx = blockIdx.x * 256 + threadIdx.x;     // t*32768 + i*32 + k
  int t  = idx >> 15;
  int ik = idx & 32767;
  float acc = 0.f;
#pragma unroll
  for (int j = 0; j < R_DIM; ++j)
    acc = fmaf(first[t * R_DIM + j], middle[j * (IN_DIM * R_DIM) + ik], acc);
  a1[idx] = acc;
}

// ---- kernel 2: w_T[t][o][i] = sum_k A1[t][i][k]*task[k][o], bf16 ----------
__global__ __launch_bounds__(256) void tt_stage2(const float* __restrict__ a1,
                                                 const float* __restrict__ task,
                                                 __hip_bfloat16* __restrict__ wT) {
  int bid = blockIdx.x;
  int t  = bid >> 8;
  int ob = (bid >> 4) & 15;
  int ib = bid & 15;
  __shared__ float A1s[64][33];
  __shared__ float Ts[32][64];
  int tid = threadIdx.x;
#pragma unroll
  for (int r = 0; r < 8; ++r) {
    int idx2 = tid + 256 * r;              // 64x32 A1 tile
    int il = idx2 >> 5, k = idx2 & 31;
    A1s[il][k] = a1[t * (IN_DIM * R_DIM) + (ib * 64 + il) * R_DIM + k];
  }
#pragma unroll
  for (int r = 0; r < 8; ++r) {
    int idx2 = tid + 256 * r;              // 32x64 task tile
    int k = idx2 >> 6, ol = idx2 & 63;
    Ts[k][ol] = task[k * OUT_DIM + ob * 64 + ol];
  }
  __syncthreads();
  int il = tid & 63;
  int og = tid >> 6;                        // 0..3
  float acc[16];
#pragma unroll
  for (int r = 0; r < 16; ++r) acc[r] = 0.f;
#pragma unroll
  for (int k = 0; k < 32; ++k) {
    float a = A1s[il][k];
#pragma unroll
    for (int r = 0; r < 16; ++r)
      acc[r] = fmaf(a, Ts[k][og * 16 + r], acc[r]);
  }
#pragma unroll
  for (int r = 0; r < 16; ++r) {
    size_t o = (size_t)ob * 64 + og * 16 + r;
    wT[((size_t)t * OUT_DIM + o) * IN_DIM + ib * 64 + il] = __float2bfloat16(acc[r]);
  }
}

// ---- kernel 3: per-task GEMM, bf16 MFMA, 128x128xBK64, m97 structure ------
// LDS (dynamic 48KB): A fp32 [128][64] swizzled at 0 (32KB),
//                     B bf16 [128(n)][64(k)] swizzled at 32768 (16KB).
// Swizzle: 16B-chunk index within a row ^= (row&7). BOTH operands staged via
// global_load_lds with pre-swizzled SOURCE + linear dest (rule 21).
// One vmem drain per K-step (top barrier); bottom barrier is lgkm-only.
// fp32->bf16 conversion inline in compute via v_perm (trunc, 1 op / 2 floats).
__global__ __launch_bounds__(256, 3) void tt_gemm(const float* __restrict__ X,
                                                  const uint16_t* __restrict__ WT,
                                                  float* __restrict__ O) {
  extern __shared__ uint8_t sm[];

  const int cpx = (T_DIM * (B_DIM / BM) * (OUT_DIM / BN)) >> 3;  // 256
  int bid = blockIdx.x;
  int l  = (bid & 7) * cpx + (bid >> 3);   // bijective XCD swizzle: XCD == t
  int t  = l >> 8;
  int mt = (l >> 3) & 31;
  int nt = l & 7;                          // n fastest -> x panel shared in L2

  const int tid  = threadIdx.x;
  const int lane = tid & 63;
  const int wave = tid >> 6;
  const int wr = wave >> 1, wc = wave & 1;

  // A staging (gload_lds, fp32): region q = wave*8+qq holds rows q*4..q*4+3
  // LDS linear byte p=q*1024+lane*16 -> row=q*4+(lane>>4), chunk=lane&15;
  // source chunk = (lane&15) ^ (row&7), row&7 = 4*(qq&1) + (lane>>4)
  const int a_lrow   = lane >> 4;          // 0..3
  const int a_lchunk = lane & 15;
  const int srcf0 = (a_lchunk ^ a_lrow) * 4;        // float offset, qq even
  const int srcf1 = (a_lchunk ^ (4 + a_lrow)) * 4;  // qq odd
  const float* xrow =
      X + (size_t)(mt * BM + wave * 32 + a_lrow) * (T_DIM * IN_DIM) + t * IN_DIM;

  // B staging (gload_lds, bf16): region = wave*4+q holds 8 rows of 128B
  const int b_rowin = lane >> 3;
  const int b_gcol  = ((lane & 7) * 16) ^ (b_rowin << 4);
  const uint16_t* wtile = WT + ((size_t)(t * OUT_DIM + nt * BN)) * IN_DIM;

  // fragment read params (16x16x32: row = lane&15, k-group = lane>>4)
  const int r0a = wr * 64 + (lane & 15);
  const int r0b = wc * 64 + (lane & 15);
  const int sA  = lane & 7;                // row&7 for fragment rows
  const int kg  = lane >> 4;
  const int kswzB = (lane & 7) << 4;

  f32x4 acc[4][4] = {};

  for (int kt = 0; kt < NKT; ++kt) {
    // ---- stage: 8 A-gloads + 4 B-gloads per wave, all async
    const float* xk = xrow + kt * BK;
#pragma unroll
    for (int qq = 0; qq < 8; ++qq) {
      gload_lds16(xk + (size_t)qq * 4 * (T_DIM * IN_DIM) + ((qq & 1) ? srcf1 : srcf0),
                  sm + (wave * 8 + qq) * 1024);
    }
    const uint16_t* wk = wtile + (size_t)kt * BK;
#pragma unroll
    for (int q = 0; q < 4; ++q) {
      int row = (wave * 4 + q) * 8 + b_rowin;
      gload_lds16((const uint8_t*)(wk + (size_t)row * IN_DIM) + b_gcol,
                  sm + 32768 + (wave * 4 + q) * 1024);
    }
    __syncthreads();   // single vmem drain point: A,B fully in LDS

    // ---- compute 32 MFMA from LDS (A: fp32 read + perm-trunc to bf16)
    const uint8_t* ab = sm;
    const uint8_t* bb = sm + 32768;
#pragma unroll
    for (int ks = 0; ks < 2; ++ks) {
      bf16x8 af[4], bfr[4];
#pragma unroll
      for (int m = 0; m < 4; ++m) {
        const int row = r0a + m * 16;          // row&7 == sA (wr*64,m*16 ≡0 mod 8)
        const int c0  = ks * 8 + kg * 2;
        f32x4 lo = *(const f32x4*)(ab + row * 256 + (((c0    ) ^ sA) << 4));
        f32x4 hi = *(const f32x4*)(ab + row * 256 + (((c0 + 1) ^ sA) << 4));
        union { uint32_t u[4]; bf16x8 v; } cv;
        cv.u[0] = __builtin_amdgcn_perm(__float_as_uint(lo.y), __float_as_uint(lo.x), 0x07060302u);
        cv.u[1] = __builtin_amdgcn_perm(__float_as_uint(lo.w), __float_as_uint(lo.z), 0x07060302u);
        cv.u[2] = __builtin_amdgcn_perm(__float_as_uint(hi.y), __float_as_uint(hi.x), 0x07060302u);
        cv.u[3] = __builtin_amdgcn_perm(__float_as_uint(hi.w), __float_as_uint(hi.z), 0x07060302u);
        af[m] = cv.v;
      }
#pragma unroll
      for (int n = 0; n < 4; ++n) {
        const int kbyte = (ks * 64 + kg * 16) ^ kswzB;
        bfr[n] = *(const bf16x8*)(bb + (r0b + n * 16) * 128 + kbyte);
      }
#pragma unroll
      for (int m = 0; m < 4; ++m)
#pragma unroll
        for (int n = 0; n < 4; ++n)
          acc[m][n] = __builtin_amdgcn_mfma_f32_16x16x32_bf16(af[m], bfr[n],
                                                              acc[m][n], 0, 0, 0);
    }
    __syncthreads();   // lgkm-only (no vmem issued in compute phase)
  }

  // ---- epilogue: C/D layout col=lane&15, row=(lane>>4)*4+j (m89-verified)
  const size_t obase =
      (size_t)(mt * BM) * (T_DIM * OUT_DIM) + (size_t)t * OUT_DIM + nt * BN;
  const int crow0 = wr * 64 + (lane >> 4) * 4;
  const int ccol  = wc * 64 + (lane & 15);
#pragma unroll
  for (int m = 0; m < 4; ++m) {
#pragma unroll
    for (int j = 0; j < 4; ++j) {
      size_t rowoff = obase + (size_t)(crow0 + m * 16 + j) * (T_DIM * OUT_DIM) + ccol;
#pragma unroll
      for (int n = 0; n < 4; ++n)
        O[rowoff + n * 16] = acc[m][n][j];
    }
  }
}

// ---- host ------------------------------------------------------------------
extern "C" void kernel_launch(void* const* d_in, const int* in_sizes, int n_in,
                              void* d_out, int out_size, void* d_ws, size_t ws_size,
                              hipStream_t stream) {
  const float* x      = (const float*)d_in[0];
  const float* first  = (const float*)d_in[1];
  const float* middle = (const float*)d_in[2];
  const float* task   = (const float*)d_in[3];
  float* out = (float*)d_out;

  // ws: A1 fp32 [8][1024][32] = 1MB at 0; w_T bf16 [8][1024][1024] = 16MB at 1MB
  float* a1 = (float*)d_ws;
  __hip_bfloat16* wT = (__hip_bfloat16*)((uint8_t*)d_ws + (1u << 20));

  tt_stage1<<<(T_DIM * IN_DIM * R_DIM) / 256, 256, 0, stream>>>(first, middle, a1);
  tt_stage2<<<T_DIM * 16 * 16, 256, 0, stream>>>(a1, task, wT);
  tt_gemm<<<T_DIM * (B_DIM / BM) * (OUT_DIM / BN), 256, 49152, stream>>>(
      x, (const uint16_t*)wT, out);
}

// Round 4
// 138.025 us; speedup vs baseline: 1.1846x; 1.0109x over previous
//
#include <hip/hip_runtime.h>
#include <hip/hip_bf16.h>
#include <stdint.h>

#define B_DIM 4096
#define T_DIM 8
#define IN_DIM 1024
#define OUT_DIM 1024
#define R_DIM 32

#define BM 256
#define BN 256
#define BK 64
#define NKT (IN_DIM / BK)   // 16

typedef __bf16 bf16x8 __attribute__((ext_vector_type(8)));
typedef float  f32x4  __attribute__((ext_vector_type(4)));

#define VMCNT(n) asm volatile("s_waitcnt vmcnt(" #n ")" ::: "memory")
#define CFENCE() asm volatile("" ::: "memory")
#define BARRIER() do { CFENCE(); __builtin_amdgcn_s_barrier(); CFENCE(); } while (0)

// ---- helpers --------------------------------------------------------------

// round-to-nearest fp32->bf16, two packed into one u32 (lo in low half)
__device__ __forceinline__ uint32_t pack2_bf16(float a, float b) {
  uint32_t ua = __float_as_uint(a), ub = __float_as_uint(b);
  ua = (ua + 0x7FFFu + ((ua >> 16) & 1u)) >> 16;
  ub = (ub + 0x7FFFu + ((ub >> 16) & 1u)) & 0xFFFF0000u;
  return ua | ub;
}

// async global->LDS, 16B per lane; LDS dest is wave-uniform base + lane*16
__device__ __forceinline__ void gload_lds16(const void* g, void* l) {
  __builtin_amdgcn_global_load_lds(
      (const __attribute__((address_space(1))) void*)(uintptr_t)g,
      (__attribute__((address_space(3))) void*)(uint32_t)(uintptr_t)l,
      16, 0, 0);
}

// stage one 16KB half-tile (128 of 256 rows, 16-row-interleaved: half =
// (row>>4)&1) of K-tile `ktn` into LDS operand region `ldsop` (32KB).
// LDS dest linear (gload_lds requirement); source chunk pre-swizzled
// (chunk ^= slot&7) so swizzled ds_reads see a conflict-free layout.
__device__ __forceinline__ void stage_half(const uint16_t* gtile, int ktn,
                                           int half, uint8_t* ldsop,
                                           int wave, int lane) {
#pragma unroll
  for (int j = 0; j < 2; ++j) {
    int s = j * 64 + wave * 8 + (lane >> 3);      // slot 0..127 within half
    int c = lane & 7;                             // LDS 16B chunk within row
    int row = (s >> 4) * 32 + half * 16 + (s & 15);
    gload_lds16((const uint8_t*)(gtile + (size_t)row * IN_DIM + ktn * BK) +
                    ((c ^ (s & 7)) << 4),
                ldsop + half * 16384 + j * 8192 + wave * 1024);
  }
}

// fragment reads: slot = (row>>5)*16 + (row&15); chunk = (ks*4+kg) ^ (row&7)
__device__ __forceinline__ bf16x8 lds_frag(const uint8_t* op, int grp /*wr8+m | wc4+n*/,
                                           int par /*m&1 | n&1*/, int ks,
                                           int l15, int kg, int l7) {
  return *(const bf16x8*)(op + par * 16384 + (grp >> 1) * 2048 + l15 * 128 +
                          ((((ks << 2) + kg) ^ l7) << 4));
}

// ---- kernel 0: x[b][t][i] fp32 -> xb[t][b][i] bf16 (RNE) -------------------
__global__ __launch_bounds__(256) void x_cvt(const float* __restrict__ x,
                                             uint16_t* __restrict__ xb) {
  int u = blockIdx.x * 256 + threadIdx.x;        // 4M threads, 8 elems each
  int i0 = (u & 127) << 3;
  int bt = u >> 7;                               // b*8 + t
  int t = bt & 7, b = bt >> 3;
  const float4* src = (const float4*)(x + (size_t)bt * IN_DIM + i0);
  float4 v0 = src[0], v1 = src[1];
  uint4 o;
  o.x = pack2_bf16(v0.x, v0.y);
  o.y = pack2_bf16(v0.z, v0.w);
  o.z = pack2_bf16(v1.x, v1.y);
  o.w = pack2_bf16(v1.z, v1.w);
  *(uint4*)(xb + ((size_t)t * B_DIM + b) * IN_DIM + i0) = o;
}

// ---- kernel 1: A1[t][i][k] = sum_j first[t][j] * middle[j][i][k] ----------
__global__ void tt_stage1(const float* __restrict__ first,
                          const float* __restrict__ middle,
                          float* __restrict__ a1) {
  int idx = blockIdx.x * 256 + threadIdx.x;     // t*32768 + i*32 + k
  int t  = idx >> 15;
  int ik = idx & 32767;
  float acc = 0.f;
#pragma unroll
  for (int j = 0; j < R_DIM; ++j)
    acc = fmaf(first[t * R_DIM + j], middle[j * (IN_DIM * R_DIM) + ik], acc);
  a1[idx] = acc;
}

// ---- kernel 2: w_T[t][o][i] = sum_k A1[t][i][k]*task[k][o], bf16 ----------
__global__ __launch_bounds__(256) void tt_stage2(const float* __restrict__ a1,
                                                 const float* __restrict__ task,
                                                 __hip_bfloat16* __restrict__ wT) {
  int bid = blockIdx.x;
  int t  = bid >> 8;
  int ob = (bid >> 4) & 15;
  int ib = bid & 15;
  __shared__ float A1s[64][33];
  __shared__ float Ts[32][64];
  int tid = threadIdx.x;
#pragma unroll
  for (int r = 0; r < 8; ++r) {
    int idx2 = tid + 256 * r;              // 64x32 A1 tile
    int il = idx2 >> 5, k = idx2 & 31;
    A1s[il][k] = a1[t * (IN_DIM * R_DIM) + (ib * 64 + il) * R_DIM + k];
  }
#pragma unroll
  for (int r = 0; r < 8; ++r) {
    int idx2 = tid + 256 * r;              // 32x64 task tile
    int k = idx2 >> 6, ol = idx2 & 63;
    Ts[k][ol] = task[k * OUT_DIM + ob * 64 + ol];
  }
  __syncthreads();
  int il = tid & 63;
  int og = tid >> 6;                        // 0..3
  float acc[16];
#pragma unroll
  for (int r = 0; r < 16; ++r) acc[r] = 0.f;
#pragma unroll
  for (int k = 0; k < 32; ++k) {
    float a = A1s[il][k];
#pragma unroll
    for (int r = 0; r < 16; ++r)
      acc[r] = fmaf(a, Ts[k][og * 16 + r], acc[r]);
  }
#pragma unroll
  for (int r = 0; r < 16; ++r) {
    size_t o = (size_t)ob * 64 + og * 16 + r;
    wT[((size_t)t * OUT_DIM + o) * IN_DIM + ib * 64 + il] = __float2bfloat16(acc[r]);
  }
}

// ---- kernel 3: 256x256xBK64 8-phase counted-vmcnt bf16 GEMM ---------------
// 8 waves (2M x 4N), per-wave 128x64 out = acc[8][4]. LDS 128KB:
// buf[P] (P=kt&1): A 32KB @P*65536, B 32KB @P*65536+32768; halves 16-row
// interleaved. Per K-tile 4 phases, quadrant (m-parity, n-parity):
//   P1(0,0): dsA[mp0](8)+dsB[np0](4); stage Ah0(kt+1); VMCNT(2*); bar; 16MFMA; bar
//   P2(0,1): dsB[np1](4);             stage Bh0(kt+1);            bar; 16MFMA; bar
//   P3(1,0): dsA[mp1](8);             stage Ah1(kt+1);            bar; 16MFMA; bar
//   P4(1,1): -;                       stage Bh1(kt+1); VMCNT(4);  bar; 16MFMA; bar
// (*: vmcnt(0) at kt==NKT-1). Counted waits keep 2-3 half-tiles in flight;
// never drain in the main loop (T4). setprio(1) around MFMA clusters (T5).
__global__ __launch_bounds__(512, 2) void tt_gemm(const uint16_t* __restrict__ XB,
                                                  const uint16_t* __restrict__ WT,
                                                  float* __restrict__ O) {
  extern __shared__ uint8_t sm[];
  int bid = blockIdx.x;
  const int t  = bid & 7;                 // task == XCD (round-robin dispatch)
  const int l  = bid >> 3;                // 0..63 within task
  const int mt = l >> 2;                  // 0..15
  const int nt = l & 3;                   // n-fastest: x panel L2-shared

  const int tid  = threadIdx.x;
  const int lane = tid & 63;
  const int wave = tid >> 6;              // 0..7
  const int wr = wave >> 2, wc = wave & 3;
  const int wr8 = wr * 8, wc4 = wc * 4;
  const int l15 = lane & 15, l7 = lane & 7, kg = lane >> 4;

  const uint16_t* gA = XB + ((size_t)t * B_DIM + mt * BM) * IN_DIM;
  const uint16_t* gB = WT + ((size_t)t * OUT_DIM + nt * BN) * IN_DIM;

  f32x4 acc[8][4] = {};
  bf16x8 afr[4][2], bfr0[2][2], bfr1[2][2];

  // ---- prologue: K-tile 0 fully into buf0, drain once
  stage_half(gA, 0, 0, sm, wave, lane);
  stage_half(gB, 0, 0, sm + 32768, wave, lane);
  stage_half(gA, 0, 1, sm, wave, lane);
  stage_half(gB, 0, 1, sm + 32768, wave, lane);
  VMCNT(0);
  BARRIER();

#pragma unroll 2
  for (int kt = 0; kt < NKT; ++kt) {
    const int P = kt & 1;
    const uint8_t* bA = sm + P * 65536;
    const uint8_t* bB = bA + 32768;
    uint8_t* nA = sm + (P ^ 1) * 65536;
    uint8_t* nB = nA + 32768;
    const bool st = (kt + 1) < NKT;

    // ===== P1: (mp0, np0)
#pragma unroll
    for (int mo = 0; mo < 4; ++mo)
#pragma unroll
      for (int ks = 0; ks < 2; ++ks)
        afr[mo][ks] = lds_frag(bA, wr8 + mo * 2, 0, ks, l15, kg, l7);
#pragma unroll
    for (int no = 0; no < 2; ++no)
#pragma unroll
      for (int ks = 0; ks < 2; ++ks)
        bfr0[no][ks] = lds_frag(bB, wc4 + no * 2, 0, ks, l15, kg, l7);
    if (st) stage_half(gA, kt + 1, 0, nA, wave, lane);
    if (kt == NKT - 1) { VMCNT(0); } else { VMCNT(2); }   // cover Ah1,Bh1(kt)
    BARRIER();
    __builtin_amdgcn_s_setprio(1);
#pragma unroll
    for (int mo = 0; mo < 4; ++mo)
#pragma unroll
      for (int no = 0; no < 2; ++no)
#pragma unroll
        for (int ks = 0; ks < 2; ++ks)
          acc[mo * 2][no * 2] = __builtin_amdgcn_mfma_f32_16x16x32_bf16(
              afr[mo][ks], bfr0[no][ks], acc[mo * 2][no * 2], 0, 0, 0);
    __builtin_amdgcn_s_setprio(0);
    BARRIER();

    // ===== P2: (mp0, np1)
#pragma unroll
    for (int no = 0; no < 2; ++no)
#pragma unroll
      for (int ks = 0; ks < 2; ++ks)
        bfr1[no][ks] = lds_frag(bB, wc4 + no * 2 + 1, 1, ks, l15, kg, l7);
    if (st) stage_half(gB, kt + 1, 0, nB, wave, lane);
    BARRIER();
    __builtin_amdgcn_s_setprio(1);
#pragma unroll
    for (int mo = 0; mo < 4; ++mo)
#pragma unroll
      for (int no = 0; no < 2; ++no)
#pragma unroll
        for (int ks = 0; ks < 2; ++ks)
          acc[mo * 2][no * 2 + 1] = __builtin_amdgcn_mfma_f32_16x16x32_bf16(
              afr[mo][ks], bfr1[no][ks], acc[mo * 2][no * 2 + 1], 0, 0, 0);
    __builtin_amdgcn_s_setprio(0);
    BARRIER();

    // ===== P3: (mp1, np0)
#pragma unroll
    for (int mo = 0; mo < 4; ++mo)
#pragma unroll
      for (int ks = 0; ks < 2; ++ks)
        afr[mo][ks] = lds_frag(bA, wr8 + mo * 2 + 1, 1, ks, l15, kg, l7);
    if (st) stage_half(gA, kt + 1, 1, nA, wave, lane);
    BARRIER();
    __builtin_amdgcn_s_setprio(1);
#pragma unroll
    for (int mo = 0; mo < 4; ++mo)
#pragma unroll
      for (int no = 0; no < 2; ++no)
#pragma unroll
        for (int ks = 0; ks < 2; ++ks)
          acc[mo * 2 + 1][no * 2] = __builtin_amdgcn_mfma_f32_16x16x32_bf16(
              afr[mo][ks], bfr0[no][ks], acc[mo * 2 + 1][no * 2], 0, 0, 0);
    __builtin_amdgcn_s_setprio(0);
    BARRIER();

    // ===== P4: (mp1, np1)
    if (st) stage_half(gB, kt + 1, 1, nB, wave, lane);
    if (st) { VMCNT(4); }                  // cover Ah0,Bh0(kt+1); keep 4 flying
    BARRIER();
    __builtin_amdgcn_s_setprio(1);
#pragma unroll
    for (int mo = 0; mo < 4; ++mo)
#pragma unroll
      for (int no = 0; no < 2; ++no)
#pragma unroll
        for (int ks = 0; ks < 2; ++ks)
          acc[mo * 2 + 1][no * 2 + 1] = __builtin_amdgcn_mfma_f32_16x16x32_bf16(
              afr[mo][ks], bfr1[no][ks], acc[mo * 2 + 1][no * 2 + 1], 0, 0, 0);
    __builtin_amdgcn_s_setprio(0);
    BARRIER();
  }

  // ---- epilogue: C/D layout col=lane&15, row=(lane>>4)*4+j (m89-verified)
  const int crow0 = mt * BM + wr * 128 + (lane >> 4) * 4;
  const int ccol0 = nt * BN + wc * 64 + (lane & 15);
#pragma unroll
  for (int m = 0; m < 8; ++m) {
#pragma unroll
    for (int j = 0; j < 4; ++j) {
      size_t rowoff =
          ((size_t)(crow0 + m * 16 + j) * T_DIM + t) * OUT_DIM + ccol0;
#pragma unroll
      for (int n = 0; n < 4; ++n)
        O[rowoff + n * 16] = acc[m][n][j];
    }
  }
}

// ---- host ------------------------------------------------------------------
extern "C" void kernel_launch(void* const* d_in, const int* in_sizes, int n_in,
                              void* d_out, int out_size, void* d_ws, size_t ws_size,
                              hipStream_t stream) {
  const float* x      = (const float*)d_in[0];
  const float* first  = (const float*)d_in[1];
  const float* middle = (const float*)d_in[2];
  const float* task   = (const float*)d_in[3];
  float* out = (float*)d_out;

  // ws: a1 fp32 1MB @0; wT bf16 16MB @1MB; xb bf16 64MB @17MB  (81MB total)
  float* a1 = (float*)d_ws;
  __hip_bfloat16* wT = (__hip_bfloat16*)((uint8_t*)d_ws + (1u << 20));
  uint16_t* xb = (uint16_t*)((uint8_t*)d_ws + (17u << 20));

  hipFuncSetAttribute((const void*)tt_gemm,
                      hipFuncAttributeMaxDynamicSharedMemorySize, 131072);

  x_cvt<<<(B_DIM * T_DIM * IN_DIM) / 8 / 256, 256, 0, stream>>>(x, xb);
  tt_stage1<<<(T_DIM * IN_DIM * R_DIM) / 256, 256, 0, stream>>>(first, middle, a1);
  tt_stage2<<<T_DIM * 16 * 16, 256, 0, stream>>>(a1, task, wT);
  tt_gemm<<<T_DIM * (B_DIM / BM) * (OUT_DIM / BN), 512, 131072, stream>>>(
      xb, (const uint16_t*)wT, out);
}